// Round 18
// baseline (379.673 us; speedup 1.0000x reference)
//
#include <hip/hip_runtime.h>
#include <stdint.h>

#define S 2048
#define HID 3584
#define NH 16
#define NKV 8
#define DH 256
#define WINDOW 1024
#define SCALE 0.0625f
#define CAP 50.0f

typedef short s16x8 __attribute__((ext_vector_type(8)));
typedef float f32x4 __attribute__((ext_vector_type(4)));

__device__ __forceinline__ short f2bf(float f) {
  union { float f; uint32_t u; } c; c.f = f;
  uint32_t u = c.u;
  uint32_t r = (u + 0x7FFFu + ((u >> 16) & 1u)) >> 16;
  return (short)r;
}
__device__ __forceinline__ float bf2f(short s) {
  union { uint32_t u; float f; } c;
  c.u = ((uint32_t)(uint16_t)s) << 16;
  return c.f;
}
__device__ __forceinline__ void gll16(const void* g, void* l) {
  __builtin_amdgcn_global_load_lds((const __attribute__((address_space(1))) void*)g,
                                   (__attribute__((address_space(3))) void*)l, 16, 0, 0);
}

// ---------------- RoPE table ----------------
__global__ void rope_table_kernel(float2* __restrict__ tbl) {
  int idx = blockIdx.x * 256 + threadIdx.x;
  int s = idx >> 7, i = idx & 127;
  float inv = __expf(-(float)i * (9.210340371976184f / 128.0f));
  float fr = (float)s * inv;
  tbl[idx] = make_float2(cosf(fr), sinf(fr));
}

// ---------------- hs fp32 -> bf16 ----------------
__global__ void conv_hs_kernel(const float* __restrict__ src, short* __restrict__ dst) {
  int gid = blockIdx.x * 256 + threadIdx.x;
  float4 a = *(const float4*)&src[(size_t)gid * 8];
  float4 b = *(const float4*)&src[(size_t)gid * 8 + 4];
  s16x8 o;
  o[0] = f2bf(a.x); o[1] = f2bf(a.y); o[2] = f2bf(a.z); o[3] = f2bf(a.w);
  o[4] = f2bf(b.x); o[5] = f2bf(b.y); o[6] = f2bf(b.z); o[7] = f2bf(b.w);
  *(s16x8*)&dst[(size_t)gid * 8] = o;
}

// ------- All W transposes fused: fp32 [K][N] -> bf16 [N][K] -------
__global__ __launch_bounds__(256)
void transpose_all_kernel(const float* __restrict__ Wq, const float* __restrict__ Wk,
                          const float* __restrict__ Wv, const float* __restrict__ Wo,
                          short* __restrict__ Wt, short* __restrict__ WtO)
{
  __shared__ __align__(16) short t[64][76];
  int b = blockIdx.x;
  const float* src; short* dst; int K, N, lb;
  if (b < 3584)      { src = Wq; dst = Wt;                       K = HID;  N = 4096; lb = b; }
  else if (b < 5376) { src = Wk; dst = Wt + (size_t)4096 * HID;  K = HID;  N = 2048; lb = b - 3584; }
  else if (b < 7168) { src = Wv; dst = Wt + (size_t)6144 * HID;  K = HID;  N = 2048; lb = b - 5376; }
  else               { src = Wo; dst = WtO;                      K = 4096; N = HID;  lb = b - 7168; }
  int ntn = N >> 6;
  int tn = lb % ntn, tk = lb / ntn;
  int tid = threadIdx.x;
  int c = tid & 63, rg = tid >> 6;
  #pragma unroll
  for (int i = 0; i < 4; ++i) {
    int r0 = i * 16 + rg * 4;
    short tmp[4];
    #pragma unroll
    for (int j = 0; j < 4; ++j)
      tmp[j] = f2bf(src[(size_t)(tk * 64 + r0 + j) * N + tn * 64 + c]);
    *(short4*)&t[c][r0] = *(short4*)tmp;
  }
  __syncthreads();
  #pragma unroll
  for (int it = 0; it < 2; ++it) {
    int flat = it * 256 + tid;
    int n = flat >> 3, kc = flat & 7;
    *(s16x8*)&dst[(size_t)(tn * 64 + n) * K + tk * 64 + kc * 8] = *(s16x8*)&t[n][kc * 8];
  }
}

// ---- V transpose: vsb [KV][S][D] -> vtb [KV][D][S] ----
__global__ __launch_bounds__(256)
void transpose_v_kernel(const short* __restrict__ vsb, short* __restrict__ vtb)
{
  __shared__ short t[64][74];
  int b = blockIdx.x;
  int kv = b >> 7;
  int rem = b & 127;
  int s0 = (rem >> 2) * 64, d0 = (rem & 3) * 64;
  const short* src = vsb + ((size_t)kv * S + s0) * DH + d0;
  short* dst = vtb + ((size_t)kv * DH + d0) * S + s0;
  int tid = threadIdx.x;
  int c = tid & 63, sb = (tid >> 6) * 16;
  #pragma unroll
  for (int ss = 0; ss < 16; ++ss)
    t[c][sb + ss] = src[(size_t)(sb + ss) * DH + c];
  __syncthreads();
  #pragma unroll
  for (int it = 0; it < 2; ++it) {
    int flat = it * 256 + tid;
    int r = flat >> 3, cc = (flat & 7) * 8;
    *(s16x8*)&dst[(size_t)r * S + cc] = *(s16x8*)&t[r][cc];
  }
}

// ====== m97-style single-buffer GEMM, 256x128 tile, BK=64, 256 thr ========
__global__ __launch_bounds__(256, 2)
void qkv_gemm_kernel(const short* __restrict__ hsb, const short* __restrict__ Wt,
                     short* __restrict__ qb, short* __restrict__ kbuf,
                     short* __restrict__ vsb)
{
  __shared__ __align__(16) short Asb[256 * 64];
  __shared__ __align__(16) short Bsb[128 * 64];
  int bid = blockIdx.x;
  int i = bid >> 3;
  int bm = i & 7;
  int bn = (bid & 7) * 8 + (i >> 3);
  int m0 = bm * 256, n0 = bn * 128;
  int tid = threadIdx.x, w = tid >> 6, lane = tid & 63;
  int lr = lane & 15, lk = lane >> 4;
  int wm = (w >> 1) * 128, wn = (w & 1) * 64;
  int r7 = lr & 7;
  int abase = (wm + lr) * 64 + ((lk ^ r7) * 8);
  int bbase = (wn + lr) * 64 + ((lk ^ r7) * 8);
  int row8 = tid >> 3;
  int colsw = ((tid & 7) ^ (row8 & 7)) * 8;
  const short* srcA = hsb + (size_t)(m0 + row8) * HID + colsw;
  const short* srcB = Wt + (size_t)(n0 + row8) * HID + colsw;
  f32x4 acc[8][4] = {};
  for (int t = 0; t < HID / 64; ++t) {
    const short* sa = srcA + t * 64;
    const short* sb = srcB + t * 64;
    #pragma unroll
    for (int r = 0; r < 8; ++r)
      gll16(sa + (size_t)(r * 32) * HID, Asb + r * 2048 + w * 512);
    #pragma unroll
    for (int r = 0; r < 4; ++r)
      gll16(sb + (size_t)(r * 32) * HID, Bsb + r * 2048 + w * 512);
    __syncthreads();
    s16x8 bf[4][2];
    #pragma unroll
    for (int nf = 0; nf < 4; ++nf)
      #pragma unroll
      for (int kh = 0; kh < 2; ++kh)
        bf[nf][kh] = *(const s16x8*)&Bsb[(bbase + nf * 16 * 64) ^ (kh * 32)];
    #pragma unroll
    for (int mh = 0; mh < 2; ++mh) {
      s16x8 af[4][2];
      #pragma unroll
      for (int mf = 0; mf < 4; ++mf)
        #pragma unroll
        for (int kh = 0; kh < 2; ++kh)
          af[mf][kh] = *(const s16x8*)&Asb[(abase + (mh * 64 + mf * 16) * 64) ^ (kh * 32)];
      __builtin_amdgcn_s_setprio(1);
      #pragma unroll
      for (int mf = 0; mf < 4; ++mf)
        #pragma unroll
        for (int nf = 0; nf < 4; ++nf) {
          acc[mh * 4 + mf][nf] = __builtin_amdgcn_mfma_f32_16x16x32_bf16(
              af[mf][0], bf[nf][0], acc[mh * 4 + mf][nf], 0, 0, 0);
          acc[mh * 4 + mf][nf] = __builtin_amdgcn_mfma_f32_16x16x32_bf16(
              af[mf][1], bf[nf][1], acc[mh * 4 + mf][nf], 0, 0, 0);
        }
      __builtin_amdgcn_s_setprio(0);
    }
    __syncthreads();
  }
  int region = (n0 < 4096) ? 0 : ((n0 < 6144) ? 1 : 2);
  #pragma unroll
  for (int m = 0; m < 8; ++m) {
    int srow_b = m0 + wm + m * 16 + lk * 4;
    #pragma unroll
    for (int n = 0; n < 4; ++n) {
      int ncol = n0 + wn + n * 16 + lr;
      #pragma unroll
      for (int r = 0; r < 4; ++r) {
        int srow = srow_b + r;
        short bv = f2bf(acc[m][n][r]);
        if (region == 0) {
          int h = ncol >> 8, d = ncol & 255;
          qb[((size_t)h * S + srow) * DH + d] = bv;
        } else if (region == 1) {
          int c = ncol - 4096; int kv = c >> 8, d = c & 255;
          kbuf[((size_t)kv * S + srow) * DH + d] = bv;
        } else {
          int c = ncol - 6144; int kv = c >> 8, d = c & 255;
          vsb[((size_t)kv * S + srow) * DH + d] = bv;
        }
      }
    }
  }
}

// ====== Output GEMM: m97-classic 128x128, BK=64, 256 thr ====
__global__ __launch_bounds__(256)
void out_gemm_kernel(const short* __restrict__ attnb, const short* __restrict__ WtO,
                     float* __restrict__ out)
{
  __shared__ __align__(16) short Asb[128 * 64];
  __shared__ __align__(16) short Bsb[128 * 64];
  int bid = blockIdx.x;
  int flat = (bid & 7) * 56 + (bid >> 3);
  int bn = flat >> 4, bm = flat & 15;
  int m0 = bm * 128, n0 = bn * 128;
  int tid = threadIdx.x, w = tid >> 6, lane = tid & 63;
  int lr = lane & 15, lk = lane >> 4;
  int wm = (w >> 1) * 64, wn = (w & 1) * 64;
  int r7 = lr & 7;
  int abase = (wm + lr) * 64 + ((lk ^ r7) * 8);
  int bbase = (wn + lr) * 64 + ((lk ^ r7) * 8);
  int row8 = tid >> 3;
  int colsw = ((tid & 7) ^ (row8 & 7)) * 8;
  const short* srcA = attnb + (size_t)(m0 + row8) * 4096 + colsw;
  const short* srcB = WtO + (size_t)(n0 + row8) * 4096 + colsw;
  f32x4 acc[4][4] = {};
  for (int t = 0; t < 4096 / 64; ++t) {
    const short* sa = srcA + t * 64;
    const short* sb = srcB + t * 64;
    #pragma unroll
    for (int r = 0; r < 4; ++r)
      gll16(sa + (size_t)(r * 32) * 4096, Asb + r * 2048 + w * 512);
    #pragma unroll
    for (int r = 0; r < 4; ++r)
      gll16(sb + (size_t)(r * 32) * 4096, Bsb + r * 2048 + w * 512);
    __syncthreads();
    s16x8 af[4][2], bf[4][2];
    #pragma unroll
    for (int f = 0; f < 4; ++f)
      #pragma unroll
      for (int kh = 0; kh < 2; ++kh) {
        af[f][kh] = *(const s16x8*)&Asb[(abase + f * 16 * 64) ^ (kh * 32)];
        bf[f][kh] = *(const s16x8*)&Bsb[(bbase + f * 16 * 64) ^ (kh * 32)];
      }
    __builtin_amdgcn_s_setprio(1);
    #pragma unroll
    for (int mf = 0; mf < 4; ++mf)
      #pragma unroll
      for (int nf = 0; nf < 4; ++nf) {
        acc[mf][nf] = __builtin_amdgcn_mfma_f32_16x16x32_bf16(
            af[mf][0], bf[nf][0], acc[mf][nf], 0, 0, 0);
        acc[mf][nf] = __builtin_amdgcn_mfma_f32_16x16x32_bf16(
            af[mf][1], bf[nf][1], acc[mf][nf], 0, 0, 0);
      }
    __builtin_amdgcn_s_setprio(0);
    __syncthreads();
  }
  #pragma unroll
  for (int mf = 0; mf < 4; ++mf) {
    int srow_b = m0 + wm + mf * 16 + lk * 4;
    #pragma unroll
    for (int nf = 0; nf < 4; ++nf) {
      int ncol = n0 + wn + nf * 16 + lr;
      #pragma unroll
      for (int r = 0; r < 4; ++r)
        out[(size_t)(srow_b + r) * HID + ncol] = acc[mf][nf][r];
    }
  }
}

// ---------------- RoPE (NeoX, in place on q and k) ----------------
__global__ void rope_kernel(short* __restrict__ qb, short* __restrict__ kbuf,
                            const float2* __restrict__ tbl)
{
  int gid = blockIdx.x * 256 + threadIdx.x;
  int row = gid >> 4, ch = gid & 15;
  short* base = (row < NH * S) ? (qb + (size_t)row * DH)
                               : (kbuf + (size_t)(row - NH * S) * DH);
  int s = row & (S - 1);
  int i0 = ch * 8;
  s16x8 x1 = *(s16x8*)(base + i0);
  s16x8 x2 = *(s16x8*)(base + 128 + i0);
  s16x8 y1, y2;
  #pragma unroll
  for (int j = 0; j < 8; ++j) {
    float2 cs = tbl[s * 128 + i0 + j];
    float a = bf2f(x1[j]), b = bf2f(x2[j]);
    y1[j] = f2bf(a * cs.x - b * cs.y);
    y2[j] = f2bf(b * cs.x + a * cs.y);
  }
  *(s16x8*)(base + i0) = y1;
  *(s16x8*)(base + 128 + i0) = y2;
}

// ----- Attention v7: k-halves as INDEPENDENT blocks + f32 partials --------
// Block = (h, qt, half): 4 waves, single-buffered K/V LDS (73 KB -> 2
// independent blocks/CU, no shared barrier -> true inter-block overlap).
// Fixed-shift softmax partials are exactly additive; combine kernel sums.
__global__ __launch_bounds__(256)
void attn_partial_kernel(const short* __restrict__ qb, const short* __restrict__ kbuf,
                         const short* __restrict__ vtb, float* __restrict__ part,
                         float* __restrict__ partL)
{
  __shared__ __align__(16) short Klds[64][256];   // 32 KB
  __shared__ __align__(16) short Vlds[256][64];   // 32 KB
  __shared__ __align__(16) short Plds[4][16][72]; // 9.2 KB
  int bid = blockIdx.x;                 // 1024 = 32 qt x 16 h x 2 half
  int qt = 31 - (bid >> 5);             // longest first (LPT)
  int rem = bid & 31;
  int h = rem >> 1, half = rem & 1;
  int kv = h >> 1;
  int q0 = qt * 64;
  int tid = threadIdx.x;
  int w = tid >> 6, lane = tid & 63;
  int lr = lane & 15, lk = lane >> 4;
  int qrow_base = q0 + w * 16;
  s16x8 qf[8];
  const short* qrow = qb + ((size_t)h * S + (qrow_base + lr)) * DH;
  #pragma unroll
  for (int kb = 0; kb < 8; ++kb)
    qf[kb] = *(const s16x8*)(qrow + kb * 32 + lk * 8);
  f32x4 acc_o[16] = {};
  float l_r[4] = {0.0f, 0.0f, 0.0f, 0.0f};
  int tlo = (q0 >= WINDOW - 1) ? ((q0 - (WINDOW - 1)) >> 6) : 0;
  int thi = q0 >> 6;
  const short* kbase = kbuf + (size_t)kv * S * DH;
  const short* vbase = vtb + (size_t)kv * DH * S;

  s16x8 kpf[8], vpf[8];
  auto loadRegs = [&](int t) {
    int k0 = t * 64;
    #pragma unroll
    for (int it = 0; it < 8; ++it) {
      int flat = it * 256 + tid;
      int r = flat >> 5, cg = flat & 31;
      kpf[it] = *(const s16x8*)(kbase + (size_t)(k0 + r) * DH + cg * 8);
    }
    #pragma unroll
    for (int it = 0; it < 8; ++it) {
      int flat = it * 256 + tid;
      int r = flat >> 3, cg = flat & 7;
      vpf[it] = *(const s16x8*)(vbase + (size_t)r * S + k0 + cg * 8);
    }
  };
  auto writeLds = [&]() {
    #pragma unroll
    for (int it = 0; it < 8; ++it) {
      int flat = it * 256 + tid;
      int r = flat >> 5, cg = flat & 31;
      *(s16x8*)&Klds[r][(cg ^ (r & 7)) * 8] = kpf[it];
    }
    #pragma unroll
    for (int it = 0; it < 8; ++it) {
      int flat = it * 256 + tid;
      int r = flat >> 3, cg = flat & 7;
      *(s16x8*)&Vlds[r][(cg ^ (r & 7)) * 8] = vpf[it];
    }
  };

  int n_all = thi - tlo + 1;
  int tg0 = tlo + half;
  int jmax = (n_all + 1 - half) >> 1;   // half 0: ceil, half 1: floor
  if (jmax > 0) loadRegs(tg0);
  for (int j = 0; j < jmax; ++j) {
    int t = tg0 + 2 * j;
    int k0 = t * 64;
    writeLds();
    __syncthreads();
    if (t + 2 <= thi) loadRegs(t + 2);
    f32x4 sc4[4] = {};
    __builtin_amdgcn_s_setprio(1);
    #pragma unroll
    for (int kb = 0; kb < 8; ++kb)
      #pragma unroll
      for (int ni = 0; ni < 4; ++ni) {
        int row = ni * 16 + lr;
        s16x8 b = *(const s16x8*)&Klds[row][(((kb << 2) | lk) ^ (row & 7)) * 8];
        sc4[ni] = __builtin_amdgcn_mfma_f32_16x16x32_bf16(qf[kb], b, sc4[ni], 0, 0, 0);
      }
    __builtin_amdgcn_s_setprio(0);
    bool interior = (k0 + 63 <= qrow_base) && (qrow_base + 15 - k0 < WINDOW);
    #pragma unroll
    for (int ni = 0; ni < 4; ++ni)
      #pragma unroll
      for (int r = 0; r < 4; ++r) {
        float raw = sc4[ni][r];
        float e = __expf(-fabsf(raw) * (2.0f * SCALE / CAP));
        float wgt = raw > 0.0f ? e : 1.0f;
        float p = __expf(-2.0f * CAP * __fdividef(wgt, 1.0f + e));
        if (!interior) {
          int qg = qrow_base + lk * 4 + r;
          int kg = k0 + ni * 16 + lr;
          bool valid = (kg <= qg) && (qg - kg < WINDOW);
          p = valid ? p : 0.0f;
        }
        sc4[ni][r] = p;
        l_r[r] += p;
      }
    #pragma unroll
    for (int ni = 0; ni < 4; ++ni)
      #pragma unroll
      for (int r = 0; r < 4; ++r)
        Plds[w][lk * 4 + r][ni * 16 + lr] = f2bf(sc4[ni][r]);
    s16x8 pa0 = *(const s16x8*)&Plds[w][lr][lk * 8];
    s16x8 pa1 = *(const s16x8*)&Plds[w][lr][32 + lk * 8];
    __builtin_amdgcn_s_setprio(1);
    #pragma unroll
    for (int df = 0; df < 16; ++df) {
      int row = df * 16 + lr;
      s16x8 b0 = *(const s16x8*)&Vlds[row][((lk ^ (row & 7)) * 8)];
      s16x8 b1 = *(const s16x8*)&Vlds[row][(((4 + lk) ^ (row & 7)) * 8)];
      acc_o[df] = __builtin_amdgcn_mfma_f32_16x16x32_bf16(pa0, b0, acc_o[df], 0, 0, 0);
      acc_o[df] = __builtin_amdgcn_mfma_f32_16x16x32_bf16(pa1, b1, acc_o[df], 0, 0, 0);
    }
    __builtin_amdgcn_s_setprio(0);
    __syncthreads();
  }
  // lane-reduce l and write f32 partials
  float* po = part + (size_t)half * S * 4096;
  float* pl = partL + (size_t)half * NH * S;
  #pragma unroll
  for (int r = 0; r < 4; ++r) {
    float v = l_r[r];
    #pragma unroll
    for (int off = 1; off < 16; off <<= 1)
      v += __shfl_xor(v, off, 64);
    int srow = qrow_base + lk * 4 + r;
    if (lr == 0) pl[(size_t)h * S + srow] = v;
    #pragma unroll
    for (int df = 0; df < 16; ++df)
      po[(size_t)srow * 4096 + h * DH + df * 16 + lr] = acc_o[df][r];
  }
}

// ----- Combine: attnb = (part0 + part1) / (l0 + l1), bf16 -----
__global__ __launch_bounds__(256)
void attn_combine_kernel(const float* __restrict__ part, const float* __restrict__ partL,
                         short* __restrict__ attnb)
{
  int gid = blockIdx.x * 256 + threadIdx.x;   // 4096 blocks; 8 f32 per thread
  size_t i0 = (size_t)gid * 8;
  int row = (int)(i0 >> 12);
  int col = (int)(i0 & 4095);
  int h = col >> 8;
  float l = partL[(size_t)h * S + row] + partL[(size_t)NH * S + (size_t)h * S + row];
  float inv = 1.0f / l;
  f32x4 a0 = *(const f32x4*)&part[i0];
  f32x4 a1 = *(const f32x4*)&part[i0 + 4];
  f32x4 b0 = *(const f32x4*)&part[(size_t)S * 4096 + i0];
  f32x4 b1 = *(const f32x4*)&part[(size_t)S * 4096 + i0 + 4];
  s16x8 o;
  #pragma unroll
  for (int j = 0; j < 4; ++j) {
    o[j]     = f2bf((a0[j] + b0[j]) * inv);
    o[4 + j] = f2bf((a1[j] + b1[j]) * inv);
  }
  *(s16x8*)&attnb[i0] = o;
}

extern "C" void kernel_launch(void* const* d_in, const int* in_sizes, int n_in,
                              void* d_out, int out_size, void* d_ws, size_t ws_size,
                              hipStream_t stream) {
  const float* hs = (const float*)d_in[0];
  const float* Wq = (const float*)d_in[2];
  const float* Wk = (const float*)d_in[3];
  const float* Wv = (const float*)d_in[4];
  const float* Wo = (const float*)d_in[5];
  float* out = (float*)d_out;
  char* ws = (char*)d_ws;
  size_t off = 0;
  float2* tbl  = (float2*)(ws + off); off += 2097152;
  short* qb    = (short*)(ws + off);  off += 16777216;           // q  [H][S][D]
  short* kbuf  = (short*)(ws + off);  off += 8388608;            // k  [KV][S][D]
  short* vtb   = (short*)(ws + off);  off += 8388608;            // vT [KV][D][S]
  short* attnb = (short*)(ws + off);  off += 16777216;           // attn [S][4096]
  size_t off_hsb = off;
  short* hsb   = (short*)(ws + off);  off += 14680064;           // hs bf16
  short* Wt    = (short*)(ws + off);  off += 58720256;           // [8192][3584]
  short* WtO   = (short*)(ws + off);  off += 29360128;           // [3584][4096]
  short* vsb   = (short*)(ws + off);  off += 8388608;            // v [KV][S][D]
  // partials alias hsb+Wt (dead after qkv_gemm): 67.1 + 0.26 <= 73.4 MB
  float* part  = (float*)(ws + off_hsb);                         // [2][S][4096]
  float* partL = (float*)(ws + off_hsb + (size_t)2 * S * 4096 * 4); // [2][NH][S]

  hipLaunchKernelGGL(rope_table_kernel, dim3(1024), dim3(256), 0, stream, tbl);
  hipLaunchKernelGGL(conv_hs_kernel, dim3(3584), dim3(256), 0, stream, hs, hsb);
  hipLaunchKernelGGL(transpose_all_kernel, dim3(10752), dim3(256), 0, stream,
                     Wq, Wk, Wv, Wo, Wt, WtO);
  hipLaunchKernelGGL(qkv_gemm_kernel, dim3(512), dim3(256), 0, stream,
                     hsb, Wt, qb, kbuf, vsb);
  hipLaunchKernelGGL(transpose_v_kernel, dim3(1024), dim3(256), 0, stream,
                     vsb, vtb);
  hipLaunchKernelGGL(rope_kernel, dim3(3072), dim3(256), 0, stream, qb, kbuf, tbl);
  hipLaunchKernelGGL(attn_partial_kernel, dim3(1024), dim3(256), 0, stream,
                     qb, kbuf, vtb, part, partL);
  hipLaunchKernelGGL(attn_combine_kernel, dim3(4096), dim3(256), 0, stream,
                     part, partL, attnb);
  hipLaunchKernelGGL(out_gemm_kernel, dim3(448), dim3(256), 0, stream,
                     attnb, WtO, out);
}

// Round 19
// 356.292 us; speedup vs baseline: 1.0656x; 1.0656x over previous
//
#include <hip/hip_runtime.h>
#include <stdint.h>

#define S 2048
#define HID 3584
#define NH 16
#define NKV 8
#define DH 256
#define WINDOW 1024
#define SCALE 0.0625f
#define CAP 50.0f

typedef short s16x8 __attribute__((ext_vector_type(8)));
typedef float f32x4 __attribute__((ext_vector_type(4)));

__device__ __forceinline__ short f2bf(float f) {
  union { float f; uint32_t u; } c; c.f = f;
  uint32_t u = c.u;
  uint32_t r = (u + 0x7FFFu + ((u >> 16) & 1u)) >> 16;
  return (short)r;
}
__device__ __forceinline__ float bf2f(short s) {
  union { uint32_t u; float f; } c;
  c.u = ((uint32_t)(uint16_t)s) << 16;
  return c.f;
}
__device__ __forceinline__ void gll16(const void* g, void* l) {
  __builtin_amdgcn_global_load_lds((const __attribute__((address_space(1))) void*)g,
                                   (__attribute__((address_space(3))) void*)l, 16, 0, 0);
}

// ------- Fused prep: RoPE table (blocks 0..1023) + hs->bf16 (1024..4607) ---
__global__ void prep_kernel(const float* __restrict__ src, short* __restrict__ dst,
                            float2* __restrict__ tbl)
{
  int b = blockIdx.x;
  if (b < 1024) {
    int idx = b * 256 + threadIdx.x;
    int s = idx >> 7, i = idx & 127;
    float inv = __expf(-(float)i * (9.210340371976184f / 128.0f));
    float fr = (float)s * inv;
    tbl[idx] = make_float2(cosf(fr), sinf(fr));
  } else {
    int gid = (b - 1024) * 256 + threadIdx.x;
    float4 a = *(const float4*)&src[(size_t)gid * 8];
    float4 bb = *(const float4*)&src[(size_t)gid * 8 + 4];
    s16x8 o;
    o[0] = f2bf(a.x); o[1] = f2bf(a.y); o[2] = f2bf(a.z); o[3] = f2bf(a.w);
    o[4] = f2bf(bb.x); o[5] = f2bf(bb.y); o[6] = f2bf(bb.z); o[7] = f2bf(bb.w);
    *(s16x8*)&dst[(size_t)gid * 8] = o;
  }
}

// ------- All W transposes fused: fp32 [K][N] -> bf16 [N][K] -------
__global__ __launch_bounds__(256)
void transpose_all_kernel(const float* __restrict__ Wq, const float* __restrict__ Wk,
                          const float* __restrict__ Wv, const float* __restrict__ Wo,
                          short* __restrict__ Wt, short* __restrict__ WtO)
{
  __shared__ __align__(16) short t[64][76];
  int b = blockIdx.x;
  const float* src; short* dst; int K, N, lb;
  if (b < 3584)      { src = Wq; dst = Wt;                       K = HID;  N = 4096; lb = b; }
  else if (b < 5376) { src = Wk; dst = Wt + (size_t)4096 * HID;  K = HID;  N = 2048; lb = b - 3584; }
  else if (b < 7168) { src = Wv; dst = Wt + (size_t)6144 * HID;  K = HID;  N = 2048; lb = b - 5376; }
  else               { src = Wo; dst = WtO;                      K = 4096; N = HID;  lb = b - 7168; }
  int ntn = N >> 6;
  int tn = lb % ntn, tk = lb / ntn;
  int tid = threadIdx.x;
  int c = tid & 63, rg = tid >> 6;
  #pragma unroll
  for (int i = 0; i < 4; ++i) {
    int r0 = i * 16 + rg * 4;
    short tmp[4];
    #pragma unroll
    for (int j = 0; j < 4; ++j)
      tmp[j] = f2bf(src[(size_t)(tk * 64 + r0 + j) * N + tn * 64 + c]);
    *(short4*)&t[c][r0] = *(short4*)tmp;
  }
  __syncthreads();
  #pragma unroll
  for (int it = 0; it < 2; ++it) {
    int flat = it * 256 + tid;
    int n = flat >> 3, kc = flat & 7;
    *(s16x8*)&dst[(size_t)(tn * 64 + n) * K + tk * 64 + kc * 8] = *(s16x8*)&t[n][kc * 8];
  }
}

// ---- V transpose: vsb [KV][S][D] -> vtb [KV][D][S] ----
__global__ __launch_bounds__(256)
void transpose_v_kernel(const short* __restrict__ vsb, short* __restrict__ vtb)
{
  __shared__ short t[64][74];
  int b = blockIdx.x;
  int kv = b >> 7;
  int rem = b & 127;
  int s0 = (rem >> 2) * 64, d0 = (rem & 3) * 64;
  const short* src = vsb + ((size_t)kv * S + s0) * DH + d0;
  short* dst = vtb + ((size_t)kv * DH + d0) * S + s0;
  int tid = threadIdx.x;
  int c = tid & 63, sb = (tid >> 6) * 16;
  #pragma unroll
  for (int ss = 0; ss < 16; ++ss)
    t[c][sb + ss] = src[(size_t)(sb + ss) * DH + c];
  __syncthreads();
  #pragma unroll
  for (int it = 0; it < 2; ++it) {
    int flat = it * 256 + tid;
    int r = flat >> 3, cc = (flat & 7) * 8;
    *(s16x8*)&dst[(size_t)r * S + cc] = *(s16x8*)&t[r][cc];
  }
}

// ====== m97-style single-buffer GEMM, 256x128 tile, BK=64, 256 thr ========
__global__ __launch_bounds__(256, 2)
void qkv_gemm_kernel(const short* __restrict__ hsb, const short* __restrict__ Wt,
                     short* __restrict__ qb, short* __restrict__ kbuf,
                     short* __restrict__ vsb)
{
  __shared__ __align__(16) short Asb[256 * 64];
  __shared__ __align__(16) short Bsb[128 * 64];
  int bid = blockIdx.x;
  int i = bid >> 3;
  int bm = i & 7;
  int bn = (bid & 7) * 8 + (i >> 3);
  int m0 = bm * 256, n0 = bn * 128;
  int tid = threadIdx.x, w = tid >> 6, lane = tid & 63;
  int lr = lane & 15, lk = lane >> 4;
  int wm = (w >> 1) * 128, wn = (w & 1) * 64;
  int r7 = lr & 7;
  int abase = (wm + lr) * 64 + ((lk ^ r7) * 8);
  int bbase = (wn + lr) * 64 + ((lk ^ r7) * 8);
  int row8 = tid >> 3;
  int colsw = ((tid & 7) ^ (row8 & 7)) * 8;
  const short* srcA = hsb + (size_t)(m0 + row8) * HID + colsw;
  const short* srcB = Wt + (size_t)(n0 + row8) * HID + colsw;
  f32x4 acc[8][4] = {};
  for (int t = 0; t < HID / 64; ++t) {
    const short* sa = srcA + t * 64;
    const short* sb = srcB + t * 64;
    #pragma unroll
    for (int r = 0; r < 8; ++r)
      gll16(sa + (size_t)(r * 32) * HID, Asb + r * 2048 + w * 512);
    #pragma unroll
    for (int r = 0; r < 4; ++r)
      gll16(sb + (size_t)(r * 32) * HID, Bsb + r * 2048 + w * 512);
    __syncthreads();
    s16x8 bf[4][2];
    #pragma unroll
    for (int nf = 0; nf < 4; ++nf)
      #pragma unroll
      for (int kh = 0; kh < 2; ++kh)
        bf[nf][kh] = *(const s16x8*)&Bsb[(bbase + nf * 16 * 64) ^ (kh * 32)];
    #pragma unroll
    for (int mh = 0; mh < 2; ++mh) {
      s16x8 af[4][2];
      #pragma unroll
      for (int mf = 0; mf < 4; ++mf)
        #pragma unroll
        for (int kh = 0; kh < 2; ++kh)
          af[mf][kh] = *(const s16x8*)&Asb[(abase + (mh * 64 + mf * 16) * 64) ^ (kh * 32)];
      __builtin_amdgcn_s_setprio(1);
      #pragma unroll
      for (int mf = 0; mf < 4; ++mf)
        #pragma unroll
        for (int nf = 0; nf < 4; ++nf) {
          acc[mh * 4 + mf][nf] = __builtin_amdgcn_mfma_f32_16x16x32_bf16(
              af[mf][0], bf[nf][0], acc[mh * 4 + mf][nf], 0, 0, 0);
          acc[mh * 4 + mf][nf] = __builtin_amdgcn_mfma_f32_16x16x32_bf16(
              af[mf][1], bf[nf][1], acc[mh * 4 + mf][nf], 0, 0, 0);
        }
      __builtin_amdgcn_s_setprio(0);
    }
    __syncthreads();
  }
  int region = (n0 < 4096) ? 0 : ((n0 < 6144) ? 1 : 2);
  #pragma unroll
  for (int m = 0; m < 8; ++m) {
    int srow_b = m0 + wm + m * 16 + lk * 4;
    #pragma unroll
    for (int n = 0; n < 4; ++n) {
      int ncol = n0 + wn + n * 16 + lr;
      #pragma unroll
      for (int r = 0; r < 4; ++r) {
        int srow = srow_b + r;
        short bv = f2bf(acc[m][n][r]);
        if (region == 0) {
          int h = ncol >> 8, d = ncol & 255;
          qb[((size_t)h * S + srow) * DH + d] = bv;
        } else if (region == 1) {
          int c = ncol - 4096; int kv = c >> 8, d = c & 255;
          kbuf[((size_t)kv * S + srow) * DH + d] = bv;
        } else {
          int c = ncol - 6144; int kv = c >> 8, d = c & 255;
          vsb[((size_t)kv * S + srow) * DH + d] = bv;
        }
      }
    }
  }
}

// ====== Output GEMM: m97-classic 128x128, BK=64, 256 thr ====
__global__ __launch_bounds__(256)
void out_gemm_kernel(const short* __restrict__ attnb, const short* __restrict__ WtO,
                     float* __restrict__ out)
{
  __shared__ __align__(16) short Asb[128 * 64];
  __shared__ __align__(16) short Bsb[128 * 64];
  int bid = blockIdx.x;
  int flat = (bid & 7) * 56 + (bid >> 3);
  int bn = flat >> 4, bm = flat & 15;
  int m0 = bm * 128, n0 = bn * 128;
  int tid = threadIdx.x, w = tid >> 6, lane = tid & 63;
  int lr = lane & 15, lk = lane >> 4;
  int wm = (w >> 1) * 64, wn = (w & 1) * 64;
  int r7 = lr & 7;
  int abase = (wm + lr) * 64 + ((lk ^ r7) * 8);
  int bbase = (wn + lr) * 64 + ((lk ^ r7) * 8);
  int row8 = tid >> 3;
  int colsw = ((tid & 7) ^ (row8 & 7)) * 8;
  const short* srcA = attnb + (size_t)(m0 + row8) * 4096 + colsw;
  const short* srcB = WtO + (size_t)(n0 + row8) * 4096 + colsw;
  f32x4 acc[4][4] = {};
  for (int t = 0; t < 4096 / 64; ++t) {
    const short* sa = srcA + t * 64;
    const short* sb = srcB + t * 64;
    #pragma unroll
    for (int r = 0; r < 4; ++r)
      gll16(sa + (size_t)(r * 32) * 4096, Asb + r * 2048 + w * 512);
    #pragma unroll
    for (int r = 0; r < 4; ++r)
      gll16(sb + (size_t)(r * 32) * 4096, Bsb + r * 2048 + w * 512);
    __syncthreads();
    s16x8 af[4][2], bf[4][2];
    #pragma unroll
    for (int f = 0; f < 4; ++f)
      #pragma unroll
      for (int kh = 0; kh < 2; ++kh) {
        af[f][kh] = *(const s16x8*)&Asb[(abase + f * 16 * 64) ^ (kh * 32)];
        bf[f][kh] = *(const s16x8*)&Bsb[(bbase + f * 16 * 64) ^ (kh * 32)];
      }
    __builtin_amdgcn_s_setprio(1);
    #pragma unroll
    for (int mf = 0; mf < 4; ++mf)
      #pragma unroll
      for (int nf = 0; nf < 4; ++nf) {
        acc[mf][nf] = __builtin_amdgcn_mfma_f32_16x16x32_bf16(
            af[mf][0], bf[nf][0], acc[mf][nf], 0, 0, 0);
        acc[mf][nf] = __builtin_amdgcn_mfma_f32_16x16x32_bf16(
            af[mf][1], bf[nf][1], acc[mf][nf], 0, 0, 0);
      }
    __builtin_amdgcn_s_setprio(0);
    __syncthreads();
  }
  #pragma unroll
  for (int mf = 0; mf < 4; ++mf) {
    int srow_b = m0 + wm + mf * 16 + lk * 4;
    #pragma unroll
    for (int nf = 0; nf < 4; ++nf) {
      int ncol = n0 + wn + nf * 16 + lr;
      #pragma unroll
      for (int r = 0; r < 4; ++r)
        out[(size_t)(srow_b + r) * HID + ncol] = acc[mf][nf][r];
    }
  }
}

// ---------------- RoPE (NeoX, in place on q and k) ----------------
__global__ void rope_kernel(short* __restrict__ qb, short* __restrict__ kbuf,
                            const float2* __restrict__ tbl)
{
  int gid = blockIdx.x * 256 + threadIdx.x;
  int row = gid >> 4, ch = gid & 15;
  short* base = (row < NH * S) ? (qb + (size_t)row * DH)
                               : (kbuf + (size_t)(row - NH * S) * DH);
  int s = row & (S - 1);
  int i0 = ch * 8;
  s16x8 x1 = *(s16x8*)(base + i0);
  s16x8 x2 = *(s16x8*)(base + 128 + i0);
  s16x8 y1, y2;
  #pragma unroll
  for (int j = 0; j < 8; ++j) {
    float2 cs = tbl[s * 128 + i0 + j];
    float a = bf2f(x1[j]), b = bf2f(x2[j]);
    y1[j] = f2bf(a * cs.x - b * cs.y);
    y2[j] = f2bf(b * cs.x + a * cs.y);
  }
  *(s16x8*)(base + i0) = y1;
  *(s16x8*)(base + 128 + i0) = y2;
}

// ---------------- Attention v5.1: 8-wave two-group k-split ----------------
__global__ __launch_bounds__(512)
void attn_kernel(const short* __restrict__ qb, const short* __restrict__ kbuf,
                 const short* __restrict__ vtb, short* __restrict__ attnb)
{
  __shared__ __align__(16) short Klds[2][64][256];   // 64 KB
  __shared__ __align__(16) short Vlds[2][256][64];   // 64 KB
  __shared__ __align__(16) short Plds[8][16][72];    // 18.4 KB
  int bid = blockIdx.x;
  int qt = 31 - (bid >> 4), h = bid & 15;
  int kv = h >> 1;
  int q0 = qt * 64;
  int tid = threadIdx.x;
  int w = tid >> 6, lane = tid & 63;
  int g = w >> 2, wsub = w & 3;
  int gtid = tid & 255;
  int lr = lane & 15, lk = lane >> 4;
  int qrow_base = q0 + wsub * 16;
  s16x8 qf[8];
  const short* qrow = qb + ((size_t)h * S + (qrow_base + lr)) * DH;
  #pragma unroll
  for (int kb = 0; kb < 8; ++kb)
    qf[kb] = *(const s16x8*)(qrow + kb * 32 + lk * 8);
  f32x4 acc_o[16] = {};
  float l_r[4] = {0.0f, 0.0f, 0.0f, 0.0f};
  int tlo = (q0 >= WINDOW - 1) ? ((q0 - (WINDOW - 1)) >> 6) : 0;
  int thi = q0 >> 6;
  const short* kbase = kbuf + (size_t)kv * S * DH;
  const short* vbase = vtb + (size_t)kv * DH * S;

  s16x8 kpf[8], vpf[8];
  auto loadRegs = [&](int t) {
    int k0 = t * 64;
    #pragma unroll
    for (int it = 0; it < 8; ++it) {
      int flat = it * 256 + gtid;
      int r = flat >> 5, cg = flat & 31;
      kpf[it] = *(const s16x8*)(kbase + (size_t)(k0 + r) * DH + cg * 8);
    }
    #pragma unroll
    for (int it = 0; it < 8; ++it) {
      int flat = it * 256 + gtid;
      int r = flat >> 3, cg = flat & 7;
      vpf[it] = *(const s16x8*)(vbase + (size_t)r * S + k0 + cg * 8);
    }
  };
  auto writeLds = [&]() {
    #pragma unroll
    for (int it = 0; it < 8; ++it) {
      int flat = it * 256 + gtid;
      int r = flat >> 5, cg = flat & 31;
      *(s16x8*)&Klds[g][r][(cg ^ (r & 7)) * 8] = kpf[it];
    }
    #pragma unroll
    for (int it = 0; it < 8; ++it) {
      int flat = it * 256 + gtid;
      int r = flat >> 3, cg = flat & 7;
      *(s16x8*)&Vlds[g][r][(cg ^ (r & 7)) * 8] = vpf[it];
    }
  };

  int tg0 = tlo + g;
  int n_all = thi - tlo + 1;
  int jmax = (n_all + 1) >> 1;
  if (tg0 <= thi) loadRegs(tg0);
  for (int j = 0; j < jmax; ++j) {
    int t = tg0 + 2 * j;
    bool active = (t <= thi);
    if (active) writeLds();
    __syncthreads();
    if (active && t + 2 <= thi) loadRegs(t + 2);
    if (active) {
      int k0 = t * 64;
      f32x4 sc4[4] = {};
      __builtin_amdgcn_s_setprio(1);
      #pragma unroll
      for (int kb = 0; kb < 8; ++kb)
        #pragma unroll
        for (int ni = 0; ni < 4; ++ni) {
          int row = ni * 16 + lr;
          s16x8 b = *(const s16x8*)&Klds[g][row][(((kb << 2) | lk) ^ (row & 7)) * 8];
          sc4[ni] = __builtin_amdgcn_mfma_f32_16x16x32_bf16(qf[kb], b, sc4[ni], 0, 0, 0);
        }
      __builtin_amdgcn_s_setprio(0);
      bool interior = (k0 + 63 <= qrow_base) && (qrow_base + 15 - k0 < WINDOW);
      #pragma unroll
      for (int ni = 0; ni < 4; ++ni)
        #pragma unroll
        for (int r = 0; r < 4; ++r) {
          float raw = sc4[ni][r];
          float e = __expf(-fabsf(raw) * (2.0f * SCALE / CAP));
          float wgt = raw > 0.0f ? e : 1.0f;
          float p = __expf(-2.0f * CAP * __fdividef(wgt, 1.0f + e));
          if (!interior) {
            int qg = qrow_base + lk * 4 + r;
            int kg = k0 + ni * 16 + lr;
            bool valid = (kg <= qg) && (qg - kg < WINDOW);
            p = valid ? p : 0.0f;
          }
          sc4[ni][r] = p;
          l_r[r] += p;
        }
      #pragma unroll
      for (int ni = 0; ni < 4; ++ni)
        #pragma unroll
        for (int r = 0; r < 4; ++r)
          Plds[w][lk * 4 + r][ni * 16 + lr] = f2bf(sc4[ni][r]);
      s16x8 pa0 = *(const s16x8*)&Plds[w][lr][lk * 8];
      s16x8 pa1 = *(const s16x8*)&Plds[w][lr][32 + lk * 8];
      __builtin_amdgcn_s_setprio(1);
      #pragma unroll
      for (int df = 0; df < 16; ++df) {
        int row = df * 16 + lr;
        s16x8 b0 = *(const s16x8*)&Vlds[g][row][((lk ^ (row & 7)) * 8)];
        s16x8 b1 = *(const s16x8*)&Vlds[g][row][(((4 + lk) ^ (row & 7)) * 8)];
        acc_o[df] = __builtin_amdgcn_mfma_f32_16x16x32_bf16(pa0, b0, acc_o[df], 0, 0, 0);
        acc_o[df] = __builtin_amdgcn_mfma_f32_16x16x32_bf16(pa1, b1, acc_o[df], 0, 0, 0);
      }
      __builtin_amdgcn_s_setprio(0);
    }
    __syncthreads();
  }
  float lsum[4];
  #pragma unroll
  for (int r = 0; r < 4; ++r) {
    float v = l_r[r];
    #pragma unroll
    for (int off = 1; off < 16; off <<= 1)
      v += __shfl_xor(v, off, 64);
    lsum[r] = v;
  }
  float* comb = (float*)&Klds[0][0][0];   // [64][256] f32
  float* lcomb = (float*)&Vlds[0][0][0];  // [64] f32
  if (g == 1) {
    #pragma unroll
    for (int df = 0; df < 16; ++df)
      #pragma unroll
      for (int r = 0; r < 4; ++r)
        comb[(size_t)(wsub * 16 + lk * 4 + r) * 256 + df * 16 + lr] = acc_o[df][r];
    if (lr == 0)
      #pragma unroll
      for (int r = 0; r < 4; ++r)
        lcomb[wsub * 16 + lk * 4 + r] = lsum[r];
  }
  __syncthreads();
  if (g == 0) {
    #pragma unroll
    for (int r = 0; r < 4; ++r) {
      int rowi = wsub * 16 + lk * 4 + r;
      float lt = lsum[r] + lcomb[rowi];
      float inv = 1.0f / lt;
      int srow = q0 + rowi;
      #pragma unroll
      for (int df = 0; df < 16; ++df) {
        float o = acc_o[df][r] + comb[(size_t)rowi * 256 + df * 16 + lr];
        attnb[(size_t)srow * (NH * DH) + h * DH + df * 16 + lr] = f2bf(o * inv);
      }
    }
  }
}

extern "C" void kernel_launch(void* const* d_in, const int* in_sizes, int n_in,
                              void* d_out, int out_size, void* d_ws, size_t ws_size,
                              hipStream_t stream) {
  const float* hs = (const float*)d_in[0];
  const float* Wq = (const float*)d_in[2];
  const float* Wk = (const float*)d_in[3];
  const float* Wv = (const float*)d_in[4];
  const float* Wo = (const float*)d_in[5];
  float* out = (float*)d_out;
  char* ws = (char*)d_ws;
  size_t off = 0;
  float2* tbl  = (float2*)(ws + off); off += 2097152;
  short* qb    = (short*)(ws + off);  off += 16777216;           // q  [H][S][D]
  short* kbuf  = (short*)(ws + off);  off += 8388608;            // k  [KV][S][D]
  short* vtb   = (short*)(ws + off);  off += 8388608;            // vT [KV][D][S]
  short* attnb = (short*)(ws + off);  off += 16777216;           // attn [S][4096]
  short* hsb   = (short*)(ws + off);  off += 14680064;           // hs bf16
  short* Wt    = (short*)(ws + off);  off += 58720256;           // [8192][3584]
  short* WtO   = (short*)(ws + off);  off += 29360128;           // [3584][4096]
  short* vsb   = (short*)(ws + off);  off += 8388608;            // v [KV][S][D]

  hipLaunchKernelGGL(prep_kernel, dim3(4608), dim3(256), 0, stream, hs, hsb, tbl);
  hipLaunchKernelGGL(transpose_all_kernel, dim3(10752), dim3(256), 0, stream,
                     Wq, Wk, Wv, Wo, Wt, WtO);
  hipLaunchKernelGGL(qkv_gemm_kernel, dim3(512), dim3(256), 0, stream,
                     hsb, Wt, qb, kbuf, vsb);
  hipLaunchKernelGGL(transpose_v_kernel, dim3(1024), dim3(256), 0, stream,
                     vsb, vtb);
  hipLaunchKernelGGL(rope_kernel, dim3(3072), dim3(256), 0, stream, qb, kbuf, tbl);
  hipLaunchKernelGGL(attn_kernel, dim3(512), dim3(512), 0, stream,
                     qb, kbuf, vtb, attnb);
  hipLaunchKernelGGL(out_gemm_kernel, dim3(448), dim3(256), 0, stream,
                     attnb, WtO, out);
}